// Round 1
// baseline (156.966 us; speedup 1.0000x reference)
//
#include <hip/hip_runtime.h>

#define NN 3072
#define F 256
#define NH 8
#define HD 32
#define ALPHA 0.2f
#define LN_EPS 1e-5f

// ---------------- Kernel A: h = x @ W^T  (N x F) ----------------
__global__ __launch_bounds__(256) void gemm_xwT(const float* __restrict__ x,
                                                const float* __restrict__ W,
                                                float* __restrict__ h) {
  __shared__ float xs[16][F];
  const int t = threadIdx.x;
  const int bi = blockIdx.x;
  for (int r = 0; r < 16; ++r) xs[r][t] = x[(size_t)(bi * 16 + r) * F + t];
  __syncthreads();
  float acc[16];
#pragma unroll
  for (int r = 0; r < 16; ++r) acc[r] = 0.f;
  const float* wrow = W + (size_t)t * F;
  for (int k = 0; k < F; k += 4) {
    const float4 w4 = *(const float4*)(wrow + k);
#pragma unroll
    for (int r = 0; r < 16; ++r) {
      const float4 xv = *(const float4*)(&xs[r][k]);
      acc[r] += w4.x * xv.x + w4.y * xv.y + w4.z * xv.z + w4.w * xv.w;
    }
  }
  for (int r = 0; r < 16; ++r) h[(size_t)(bi * 16 + r) * F + t] = acc[r];
}

// ---------------- Kernel B: a_src/a_dst = einsum(nhd,hd->nh) ----------------
__global__ __launch_bounds__(256) void head_proj(const float* __restrict__ h,
                                                 const float* __restrict__ asrc_w,
                                                 const float* __restrict__ adst_w,
                                                 float* __restrict__ a_src,
                                                 float* __restrict__ a_dst) {
  const int idx = blockIdx.x * 256 + threadIdx.x;  // i*8 + head
  const int i = idx >> 3, hh = idx & 7;
  const float* hp = h + (size_t)i * F + hh * HD;
  const float* ws_ = asrc_w + hh * HD;
  const float* wd_ = adst_w + hh * HD;
  float s1 = 0.f, s2 = 0.f;
#pragma unroll
  for (int d = 0; d < HD; ++d) {
    const float v = hp[d];
    s1 += v * ws_[d];
    s2 += v * wd_[d];
  }
  a_src[idx] = s1;
  a_dst[idx] = s2;
}

// ---------------- Kernel C: sparse masked multi-head attention ----------------
// One block per node i. Compact nonzero adjacency entries (order-preserving,
// deterministic), two-pass softmax over neighbors, coalesced feature gathers.
__global__ __launch_bounds__(256) void gat_attn(const float* __restrict__ adj,
                                                const float* __restrict__ hfeat,
                                                const float* __restrict__ a_src,
                                                const float* __restrict__ a_dst,
                                                const float* __restrict__ edge_W,
                                                const float* __restrict__ edge_b,
                                                float* __restrict__ h_out) {
  __shared__ unsigned short eidx[NN];
  __shared__ float evalv[NN];
  __shared__ int psum[256];
  __shared__ float wmax[4][NH];
  const int t = threadIdx.x;
  const int i = blockIdx.x;
  const float* arow = adj + (size_t)i * NN;

  // Each thread owns 12 contiguous adjacency entries.
  const float4 r0 = *(const float4*)(arow + t * 12);
  const float4 r1 = *(const float4*)(arow + t * 12 + 4);
  const float4 r2 = *(const float4*)(arow + t * 12 + 8);
  const float v[12] = {r0.x, r0.y, r0.z, r0.w, r1.x, r1.y, r1.z, r1.w,
                       r2.x, r2.y, r2.z, r2.w};
  int c = 0;
#pragma unroll
  for (int q = 0; q < 12; ++q) c += (v[q] > 0.f) ? 1 : 0;
  psum[t] = c;
  __syncthreads();
  // Hillis-Steele inclusive scan over 256 counts.
  for (int off = 1; off < 256; off <<= 1) {
    const int add = (t >= off) ? psum[t - off] : 0;
    __syncthreads();
    psum[t] += add;
    __syncthreads();
  }
  int wofs = psum[t] - c;  // exclusive prefix
  const int cnt = psum[255];
#pragma unroll
  for (int q = 0; q < 12; ++q) {
    if (v[q] > 0.f) {
      eidx[wofs] = (unsigned short)(t * 12 + q);
      evalv[wofs] = v[q];
      ++wofs;
    }
  }
  __syncthreads();

  // Phase 1: per-head running max over this thread's share of entries.
  float base[NH], ew[NH], mx[NH];
#pragma unroll
  for (int hh = 0; hh < NH; ++hh) {
    base[hh] = a_src[i * NH + hh] + edge_b[hh];
    ew[hh] = edge_W[hh];
    mx[hh] = -1e30f;
  }
  for (int e = t; e < cnt; e += 256) {
    const int j = eidx[e];
    const float av = evalv[e];
    const float4 ad0 = *(const float4*)(a_dst + j * NH);
    const float4 ad1 = *(const float4*)(a_dst + j * NH + 4);
    const float adv[8] = {ad0.x, ad0.y, ad0.z, ad0.w, ad1.x, ad1.y, ad1.z, ad1.w};
#pragma unroll
    for (int hh = 0; hh < NH; ++hh) {
      float l = base[hh] + adv[hh] + av * ew[hh];
      l = (l >= 0.f) ? l : ALPHA * l;
      mx[hh] = fmaxf(mx[hh], l);
    }
  }
#pragma unroll
  for (int off = 1; off < 64; off <<= 1) {
#pragma unroll
    for (int hh = 0; hh < NH; ++hh) mx[hh] = fmaxf(mx[hh], __shfl_xor(mx[hh], off));
  }
  if ((t & 63) == 0) {
#pragma unroll
    for (int hh = 0; hh < NH; ++hh) wmax[t >> 6][hh] = mx[hh];
  }
  __syncthreads();

  // Phase 2: one feature per thread; weights recomputed per neighbor.
  const int hh = t >> 5;
  const float mF = fmaxf(fmaxf(wmax[0][hh], wmax[1][hh]),
                         fmaxf(wmax[2][hh], wmax[3][hh]));
  const float baseF = a_src[i * NH + hh] + edge_b[hh];
  const float ewF = edge_W[hh];
  float acc = 0.f, s = 0.f;
#pragma unroll 4
  for (int e = 0; e < cnt; ++e) {
    const int j = eidx[e];
    const float av = evalv[e];
    float l = baseF + a_dst[j * NH + hh] + av * ewF;
    l = (l >= 0.f) ? l : ALPHA * l;
    const float w = __expf(l - mF);
    s += w;
    acc += w * hfeat[(size_t)j * F + t];
  }
  h_out[(size_t)i * F + t] = acc / s;
}

// ---------------- Kernel D: y = h_out @ fuse_W^T + b, LayerNorm, ReLU ----------------
__global__ __launch_bounds__(256) void fuse_ln(const float* __restrict__ hin,
                                               const float* __restrict__ fW,
                                               const float* __restrict__ fb,
                                               const float* __restrict__ ln_g,
                                               const float* __restrict__ ln_b,
                                               float* __restrict__ out) {
  __shared__ float xs[16][F];
  __shared__ float ys[16][F];
  __shared__ float mu_s[16], rs_s[16];
  const int t = threadIdx.x;
  const int bi = blockIdx.x;
  for (int r = 0; r < 16; ++r) xs[r][t] = hin[(size_t)(bi * 16 + r) * F + t];
  __syncthreads();
  float acc[16];
#pragma unroll
  for (int r = 0; r < 16; ++r) acc[r] = 0.f;
  const float* wrow = fW + (size_t)t * F;
  for (int k = 0; k < F; k += 4) {
    const float4 w4 = *(const float4*)(wrow + k);
#pragma unroll
    for (int r = 0; r < 16; ++r) {
      const float4 xv = *(const float4*)(&xs[r][k]);
      acc[r] += w4.x * xv.x + w4.y * xv.y + w4.z * xv.z + w4.w * xv.w;
    }
  }
  const float fbt = fb[t];
  for (int r = 0; r < 16; ++r) ys[r][t] = acc[r] + fbt;
  __syncthreads();
  {
    const int r = t >> 4, c0 = t & 15;
    float sm = 0.f, sq = 0.f;
    for (int cc = c0; cc < F; cc += 16) {
      const float vv = ys[r][cc];
      sm += vv;
      sq += vv * vv;
    }
#pragma unroll
    for (int off = 1; off < 16; off <<= 1) {
      sm += __shfl_xor(sm, off);
      sq += __shfl_xor(sq, off);
    }
    if (c0 == 0) {
      const float mu = sm * (1.f / F);
      const float var = sq * (1.f / F) - mu * mu;
      mu_s[r] = mu;
      rs_s[r] = rsqrtf(var + LN_EPS);
    }
  }
  __syncthreads();
  const float g = ln_g[t], b = ln_b[t];
  for (int r = 0; r < 16; ++r) {
    const float vv = (ys[r][t] - mu_s[r]) * rs_s[r] * g + b;
    out[(size_t)(bi * 16 + r) * F + t] = fmaxf(vv, 0.f);
  }
}

extern "C" void kernel_launch(void* const* d_in, const int* in_sizes, int n_in,
                              void* d_out, int out_size, void* d_ws, size_t ws_size,
                              hipStream_t stream) {
  const float* x = (const float*)d_in[0];
  const float* adj = (const float*)d_in[1];
  const float* W = (const float*)d_in[2];
  const float* attn_src = (const float*)d_in[3];
  const float* attn_dst = (const float*)d_in[4];
  const float* edge_W = (const float*)d_in[5];
  const float* edge_b = (const float*)d_in[6];
  const float* fuse_W = (const float*)d_in[7];
  const float* fuse_b = (const float*)d_in[8];
  const float* ln_g = (const float*)d_in[9];
  const float* ln_b = (const float*)d_in[10];
  float* out = (float*)d_out;

  float* ws = (float*)d_ws;
  float* h = ws;                              // N*F
  float* a_src = h + (size_t)NN * F;          // N*8
  float* a_dst = a_src + (size_t)NN * NH;     // N*8
  float* h_out = a_dst + (size_t)NN * NH;     // N*F

  gemm_xwT<<<NN / 16, 256, 0, stream>>>(x, W, h);
  head_proj<<<NN * NH / 256, 256, 0, stream>>>(h, attn_src, attn_dst, a_src, a_dst);
  gat_attn<<<NN, 256, 0, stream>>>(adj, h, a_src, a_dst, edge_W, edge_b, h_out);
  fuse_ln<<<NN / 16, 256, 0, stream>>>(h_out, fuse_W, fuse_b, ln_g, ln_b, out);
}